// Round 10
// baseline (670.179 us; speedup 1.0000x reference)
//
#include <hip/hip_runtime.h>
#include <hip/hip_bf16.h>

typedef __attribute__((ext_vector_type(4))) float float4v;
typedef __attribute__((ext_vector_type(8))) __bf16 bf16x8;
typedef __attribute__((ext_vector_type(8))) unsigned short ushort8v;

constexpr int NTOK = 50176;
constexpr int DIM  = 384;
constexpr int HID  = 1536;
constexpr int BM   = 64;          // tokens/block
constexpr int NTH  = 512;
constexpr int NBLK = NTOK / BM;   // 784
constexpr int CHW  = 32;          // hidden chunk width
constexpr int NCH  = HID / CHW;   // 48

// workspace (byte offsets) — bf16 images, 24KB per chunk
// W1-type ([32 f][384 d], 768B rows, PRE-SWIZZLED ^(r&7)<<4): written linear, read XOR'd
// W2-type ([384 d][32 k], 64B rows, LINEAR): written with 72B-row padding, read padded
constexpr int IMG_WD  = 0;                      // swz   [32][384]
constexpr int IMG_WUP = 24576;                  // lin   [384][32]
constexpr int IMG_W1  = 49152;                  // 48 x swz [32][384]
constexpr int IMG_W2  = 49152 + 48 * 24576;     // 48 x lin [384][32]
constexpr size_t WS_NEED = 2408448;
constexpr int NELEMS = 1204224;

// LDS (80 KiB/block => 2 blocks/CU exactly fills 160K)
constexpr int L_X  = 0;        // 48K   X [64][384] bf16, 768B rows, swz (r&7)<<4
constexpr int L_W  = 49152;    // 27648 W buffer: W1c linear-24576 | W2c padded 384x72B
constexpr int L_HS = 76800;    // 4608  Hs [64 tok][32 f] bf16, 72B rows
constexpr int LDSZ = 81920;

__device__ __forceinline__ unsigned short f2bf(float f) {
  __hip_bfloat16 h = __float2bfloat16(f);
  return *reinterpret_cast<unsigned short*>(&h);
}

__device__ __forceinline__ float gelu_f(float v) {
  float u = 0.7978845608f * (v + 0.044715f * v * v * v);
  float e = __expf(2.0f * u);
  float t = 1.0f - 2.0f / (e + 1.0f);
  return 0.5f * v * (1.0f + t);
}

// ---- T14 split staging: issue loads early (st persists ~one phase), write late ----
__device__ __forceinline__ void st_load(const char* src, int tid, ushort8v st[3]) {
  #pragma unroll
  for (int j = 0; j < 3; ++j)
    st[j] = *(const ushort8v*)(src + tid * 16 + j * 8192);
}
// linear 24KB write (W1-type; image pre-swizzled)
__device__ __forceinline__ void st_wr_lin(char* dst, int tid, const ushort8v st[3]) {
  #pragma unroll
  for (int j = 0; j < 3; ++j)
    *(ushort8v*)(dst + tid * 16 + j * 8192) = st[j];
}
// padded write (W2-type): linear byte b -> row d=b/64 at 72B stride (bank-spread)
__device__ __forceinline__ void st_wr_pad(char* dst, int tid, const ushort8v st[3]) {
  #pragma unroll
  for (int j = 0; j < 3; ++j) {
    int b = j * 8192 + tid * 16;
    *(ushort8v*)(dst + (b >> 6) * 72 + (b & 63)) = st[j];
  }
}

// ---------------- pack kernel ----------------
__global__ __launch_bounds__(256) void pack_k(
    const float* __restrict__ W1, const float* __restrict__ W2,
    const float* __restrict__ wd, const float* __restrict__ wu,
    unsigned short* __restrict__ img)
{
  int i = blockIdx.x * 256 + threadIdx.x;
  if (i >= NELEMS) return;
  if (i < 12288) {                               // WD swz: [32 r][384 d] 768B rows ^(r&7)<<4
    int r = i / 384; int inb = (i % 384) * 2;
    int d = (inb ^ ((r & 7) << 4)) >> 1;
    float v = (r < 24) ? wd[(r >> 3) * (DIM * 8) + d * 8 + (r & 7)] : 0.f;
    img[i] = f2bf(v);
  } else if (i < 24576) {                        // WUP linear: [384 d][32 c]
    int j = i - 12288;
    int d = j / 32, c = j % 32;
    float v = (c < 24) ? wu[c * DIM + d] : 0.f;
    img[i] = f2bf(v);
  } else if (i < 24576 + 48 * 12288) {           // W1 chunks swz: [32 f][384 d]
    int j = i - 24576; int h = j / 12288; int jc = j % 12288;
    int f = jc / 384; int inb = (jc % 384) * 2;
    int d = (inb ^ ((f & 7) << 4)) >> 1;
    img[i] = f2bf(W1[d * HID + h * CHW + f]);
  } else {                                       // W2 chunks linear: [384 d][32 k]
    int j = i - 24576 - 48 * 12288; int h = j / 12288; int jc = j % 12288;
    int d = jc / 32, k = jc % 32;
    img[i] = f2bf(W2[(h * CHW + k) * DIM + d]);
  }
}

// ---------------- fused MLP + MoE-LoRA ----------------
__global__ __launch_bounds__(NTH, 4) void fused_k(
    const float* __restrict__ x,
    const float* __restrict__ tp,
    const int*   __restrict__ ti,
    const float* __restrict__ b1,
    const float* __restrict__ b2,
    const unsigned short* __restrict__ img,
    float* __restrict__ out)
{
  extern __shared__ char lds[];
  const int tid = threadIdx.x, wid = tid >> 6, lane = tid & 63;
  const int lrow = lane & 15, g4 = lane >> 4;
  const int blockRow = blockIdx.x * BM;
  const char* imgc = (const char*)img;

  const int band = wid >> 1, chh = wid & 1;      // G1 grid: 4 bands x 2 col-halves
  const int wr = wid >> 2, wc = wid & 3;         // G2 grid: 2M x 4N

  ushort8v st[3];                                // 12 regs; T14 staging

  // ---- prologue: issue WD; X f32->bf16 -> L_X (swizzled) ----
  st_load(imgc + IMG_WD, tid, st);
  {
    const float* xb = x + (size_t)blockRow * DIM;
    #pragma unroll
    for (int it = 0; it < 6; ++it) {
      int idx = it * NTH + tid;
      int row = idx / 48, c8 = idx % 48;
      float4v v0 = *(const float4v*)(xb + row * DIM + c8 * 8);
      float4v v1 = *(const float4v*)(xb + row * DIM + c8 * 8 + 4);
      ushort8v u;
      u[0]=f2bf(v0[0]); u[1]=f2bf(v0[1]); u[2]=f2bf(v0[2]); u[3]=f2bf(v0[3]);
      u[4]=f2bf(v1[0]); u[5]=f2bf(v1[1]); u[6]=f2bf(v1[2]); u[7]=f2bf(v1[3]);
      int byte = (row * 768 + c8 * 16) ^ ((row & 7) << 4);
      *(ushort8v*)(lds + L_X + byte) = u;
    }
  }
  __syncthreads();                               // X visible; WD landed
  st_wr_lin(lds + L_W, tid, st);                 // WD -> L_W
  st_load(imgc + IMG_WUP, tid, st);              // WUP; lands under G1-moe
  __syncthreads();                               // WD visible

  // ---- G1-moe: t1 = X @ WdT -> [64][32]; prob*gelu -> Hs ----
  {
    float4v hv = {};
    int raX = band * 16 + lrow, sA = (raX & 7) << 4, baX = raX * 768 + g4 * 16;
    int rbW = chh * 16 + lrow, sB = (rbW & 7) << 4, baW = rbW * 768 + g4 * 16;
    #pragma unroll
    for (int ks = 0; ks < 12; ++ks) {
      bf16x8 a = *(const bf16x8*)(lds + L_X + ((baX + ks * 64) ^ sA));
      bf16x8 b = *(const bf16x8*)(lds + L_W + ((baW + ks * 64) ^ sB));
      hv = __builtin_amdgcn_mfma_f32_16x16x32_bf16(a, b, hv, 0, 0, 0);
    }
    int colc = chh * 16 + lrow; int e = colc >> 3;
    #pragma unroll
    for (int r = 0; r < 4; ++r) {
      int row = band * 16 + g4 * 4 + r;
      int token = blockRow + row;
      float p = 0.f;
      if (e < 3) {
        int i0 = ti[token * 2], i1 = ti[token * 2 + 1];
        if (i0 == e) p += tp[token * 2];
        if (i1 == e) p += tp[token * 2 + 1];
      }
      float gv = p * gelu_f(hv[r]);
      *(unsigned short*)(lds + L_HS + row * 72 + colc * 2) = f2bf(gv);
    }
  }
  __syncthreads();                               // Hs visible; L_W readers done; WUP landed
  st_wr_pad(lds + L_W, tid, st);                 // WUP -> L_W (72B rows)
  st_load(imgc + IMG_W1, tid, st);               // W1[0]; lands under G2-moe
  __syncthreads();                               // WUP visible

  // ---- G2-moe: acc = Hs @ WupT (K=32) ----
  float4v acc[2][6] = {};
  {
    bf16x8 A[2];
    #pragma unroll
    for (int mt = 0; mt < 2; ++mt) {
      int ra = wr * 32 + mt * 16 + lrow;
      A[mt] = *(const bf16x8*)(lds + L_HS + ra * 72 + g4 * 16);
    }
    #pragma unroll
    for (int nt = 0; nt < 6; ++nt) {
      int rd = wc * 96 + nt * 16 + lrow;
      bf16x8 b = *(const bf16x8*)(lds + L_W + rd * 72 + g4 * 16);
      acc[0][nt] = __builtin_amdgcn_mfma_f32_16x16x32_bf16(A[0], b, acc[0][nt], 0, 0, 0);
      acc[1][nt] = __builtin_amdgcn_mfma_f32_16x16x32_bf16(A[1], b, acc[1][nt], 0, 0, 0);
    }
  }

  // ---- main loop: 48 chunks; 4 barriers/chunk; T14-split staging throughout ----
  for (int h = 0; h < NCH; ++h) {
    __syncthreads();                             // (a) L_W readers done; W1[h] landed
    st_wr_lin(lds + L_W, tid, st);               // W1[h] -> L_W
    st_load(imgc + IMG_W2 + h * 24576, tid, st); // W2[h]; lands under G1
    __syncthreads();                             // (b) W1c visible

    // G1: H = X @ W1c -> [64][32]
    float4v hv = {};
    {
      int raX = band * 16 + lrow, sA = (raX & 7) << 4, baX = raX * 768 + g4 * 16;
      int rbW = chh * 16 + lrow, sB = (rbW & 7) << 4, baW = rbW * 768 + g4 * 16;
      #pragma unroll
      for (int ks = 0; ks < 12; ++ks) {
        bf16x8 a = *(const bf16x8*)(lds + L_X + ((baX + ks * 64) ^ sA));
        bf16x8 b = *(const bf16x8*)(lds + L_W + ((baW + ks * 64) ^ sB));
        hv = __builtin_amdgcn_mfma_f32_16x16x32_bf16(a, b, hv, 0, 0, 0);
      }
    }
    // bias + gelu -> Hs (72B rows)
    {
      int colc = chh * 16 + lrow;
      float bb = b1[h * CHW + colc];
      #pragma unroll
      for (int r = 0; r < 4; ++r) {
        int row = band * 16 + g4 * 4 + r;
        float gv = gelu_f(hv[r] + bb);
        *(unsigned short*)(lds + L_HS + row * 72 + colc * 2) = f2bf(gv);
      }
    }
    __syncthreads();                             // (c) Hs visible; L_W readers done; W2[h] landed
    st_wr_pad(lds + L_W, tid, st);               // W2[h] -> L_W (72B rows)
    if (h < NCH - 1)
      st_load(imgc + IMG_W1 + (h + 1) * 24576, tid, st);  // W1[h+1]; lands under G2
    __syncthreads();                             // (d) W2c visible

    // G2: acc += Hs @ W2c (K=32)
    {
      bf16x8 A[2];
      #pragma unroll
      for (int mt = 0; mt < 2; ++mt) {
        int ra = wr * 32 + mt * 16 + lrow;
        A[mt] = *(const bf16x8*)(lds + L_HS + ra * 72 + g4 * 16);
      }
      #pragma unroll
      for (int nt = 0; nt < 6; ++nt) {
        int rd = wc * 96 + nt * 16 + lrow;
        bf16x8 b = *(const bf16x8*)(lds + L_W + rd * 72 + g4 * 16);
        acc[0][nt] = __builtin_amdgcn_mfma_f32_16x16x32_bf16(A[0], b, acc[0][nt], 0, 0, 0);
        acc[1][nt] = __builtin_amdgcn_mfma_f32_16x16x32_bf16(A[1], b, acc[1][nt], 0, 0, 0);
      }
    }
  }

  // ---- epilogue: + b2, store f32 ----
  #pragma unroll
  for (int nt = 0; nt < 6; ++nt) {
    int col = wc * 96 + nt * 16 + lrow;
    float bb = b2[col];
    #pragma unroll
    for (int mt = 0; mt < 2; ++mt) {
      #pragma unroll
      for (int r = 0; r < 4; ++r) {
        int row = wr * 32 + mt * 16 + g4 * 4 + r;
        out[(size_t)(blockRow + row) * DIM + col] = acc[mt][nt][r] + bb;
      }
    }
  }
}

extern "C" void kernel_launch(void* const* d_in, const int* in_sizes, int n_in,
                              void* d_out, int out_size, void* d_ws, size_t ws_size,
                              hipStream_t stream) {
  const float* x          = (const float*)d_in[0];
  const float* topk_probs = (const float*)d_in[2];
  const int*   topk_idx   = (const int*)  d_in[3];
  const float* w_down     = (const float*)d_in[4];
  const float* w_up       = (const float*)d_in[5];
  const float* W1         = (const float*)d_in[6];
  const float* b1         = (const float*)d_in[7];
  const float* W2         = (const float*)d_in[8];
  const float* b2         = (const float*)d_in[9];
  float* out = (float*)d_out;

  if (ws_size < WS_NEED) return;

  hipFuncSetAttribute(reinterpret_cast<const void*>(fused_k),
                      hipFuncAttributeMaxDynamicSharedMemorySize, LDSZ);

  unsigned short* img = (unsigned short*)d_ws;
  pack_k<<<(NELEMS + 255) / 256, 256, 0, stream>>>(W1, W2, w_down, w_up, img);
  fused_k<<<NBLK, NTH, LDSZ, stream>>>(x, topk_probs, topk_idx, b1, b2, img, out);
}

// Round 11
// 284.051 us; speedup vs baseline: 2.3594x; 2.3594x over previous
//
#include <hip/hip_runtime.h>
#include <hip/hip_bf16.h>

typedef __attribute__((ext_vector_type(4))) float float4v;
typedef __attribute__((ext_vector_type(8))) __bf16 bf16x8;
typedef __attribute__((ext_vector_type(8))) unsigned short ushort8v;

constexpr int NTOK = 50176;
constexpr int DIM  = 384;
constexpr int HID  = 1536;
constexpr int BM   = 64;          // tokens/block
constexpr int NTH  = 512;
constexpr int NBLK = NTOK / BM;   // 784
constexpr int CHW  = 32;          // hidden chunk width
constexpr int NCH  = HID / CHW;   // 48

// workspace (byte offsets) — bf16 images, 24KB per chunk, ALL staged as linear copies
// W1-type [32 f][384 d]: 768B rows, pre-swizzled ^(f&7)<<4 (proven R2-R8)
// W2-type [384 d][32 k]: group-tiled [d/8][k/8][d%8][k%8] — aligned + conflict-free reads
constexpr int IMG_WD  = 0;                      // W1-type [32][384]
constexpr int IMG_WUP = 24576;                  // W2-type [384][32]
constexpr int IMG_W1  = 49152;                  // 48 x W1-type
constexpr int IMG_W2  = 49152 + 48 * 24576;     // 48 x W2-type
constexpr size_t WS_NEED = 2408448;
constexpr int NELEMS = 1204224;

// LDS (76 KiB/block => 2 blocks/CU)
constexpr int L_X  = 0;        // 48K   X [64][384] bf16, 768B rows, swz (r&7)<<4
constexpr int L_W  = 49152;    // 24K   W buffer (WD/W1c: swz rows | WUP/W2c: group-tiled)
constexpr int L_HS = 73728;    // 4K    Hs [64 tok][32 f] group-tiled
constexpr int LDSZ = 77824;

__device__ __forceinline__ unsigned short f2bf(float f) {
  __hip_bfloat16 h = __float2bfloat16(f);
  return *reinterpret_cast<unsigned short*>(&h);
}

__device__ __forceinline__ float gelu_f(float v) {
  float u = 0.7978845608f * (v + 0.044715f * v * v * v);
  float e = __expf(2.0f * u);
  float t = 1.0f - 2.0f / (e + 1.0f);
  return 0.5f * v * (1.0f + t);
}

// group-tiled byte address for [rows][32 cols] bf16: row r, 16B k-slot s
//   addr = (r/8)*512 + s*128 + (r%8)*16   -> read starts 4*(r&7) mod 32: 2-way, free
__device__ __forceinline__ int gt_addr(int r, int s) {
  return ((r >> 3) << 9) + (s << 7) + ((r & 7) << 4);
}

// ---- staging: load issued right after a barrier, written after the NEXT barrier ----
__device__ __forceinline__ void st_load(const char* src, int tid, ushort8v st[3]) {
  #pragma unroll
  for (int j = 0; j < 3; ++j)
    st[j] = *(const ushort8v*)(src + tid * 16 + j * 8192);
}
__device__ __forceinline__ void st_wr(char* dst, int tid, const ushort8v st[3]) {
  #pragma unroll
  for (int j = 0; j < 3; ++j)
    *(ushort8v*)(dst + tid * 16 + j * 8192) = st[j];
}

// ---------------- pack kernel ----------------
__global__ __launch_bounds__(256) void pack_k(
    const float* __restrict__ W1, const float* __restrict__ W2,
    const float* __restrict__ wd, const float* __restrict__ wu,
    unsigned short* __restrict__ img)
{
  int i = blockIdx.x * 256 + threadIdx.x;
  if (i >= NELEMS) return;
  if (i < 12288) {                               // WD (W1-type): [32 f][384 d] swz
    int f = i / 384; int inb = (i % 384) * 2;
    int d = (inb ^ ((f & 7) << 4)) >> 1;
    float v = (f < 24) ? wd[(f >> 3) * (DIM * 8) + d * 8 + (f & 7)] : 0.f;
    img[i] = f2bf(v);
  } else if (i < 24576) {                        // WUP (W2-type group-tiled)
    int j = i - 12288;
    int d = (j >> 8) * 8 + ((j >> 3) & 7);
    int k = ((j >> 6) & 3) * 8 + (j & 7);
    float v = (k < 24) ? wu[k * DIM + d] : 0.f;
    img[i] = f2bf(v);
  } else if (i < 24576 + 48 * 12288) {           // W1 chunks (W1-type): [32 f][384 d] swz
    int j = i - 24576; int h = j / 12288; int jc = j % 12288;
    int f = jc / 384; int inb = (jc % 384) * 2;
    int d = (inb ^ ((f & 7) << 4)) >> 1;
    img[i] = f2bf(W1[d * HID + h * CHW + f]);
  } else {                                       // W2 chunks (W2-type group-tiled)
    int j = i - 24576 - 48 * 12288; int h = j / 12288; int jc = j % 12288;
    int d = (jc >> 8) * 8 + ((jc >> 3) & 7);
    int k = ((jc >> 6) & 3) * 8 + (jc & 7);
    img[i] = f2bf(W2[(h * CHW + k) * DIM + d]);
  }
}

// ---------------- fused MLP + MoE-LoRA ----------------
__global__ __launch_bounds__(NTH, 4) void fused_k(
    const float* __restrict__ x,
    const float* __restrict__ tp,
    const int*   __restrict__ ti,
    const float* __restrict__ b1,
    const float* __restrict__ b2,
    const unsigned short* __restrict__ img,
    float* __restrict__ out)
{
  extern __shared__ char lds[];
  const int tid = threadIdx.x, wid = tid >> 6, lane = tid & 63;
  const int lrow = lane & 15, g4 = lane >> 4;
  const int blockRow = blockIdx.x * BM;
  const char* imgc = (const char*)img;

  const int band = wid >> 1, chh = wid & 1;      // G1 grid: 4 bands x 2 col-halves
  const int wr = wid >> 2, wc = wid & 3;         // G2 grid: 2M x 4N

  ushort8v st[3];                                // 12 regs; one pending stage at a time

  // ---- prologue: issue WD; X f32->bf16 -> L_X (swizzled) ----
  st_load(imgc + IMG_WD, tid, st);
  {
    const float* xb = x + (size_t)blockRow * DIM;
    #pragma unroll
    for (int it = 0; it < 6; ++it) {
      int idx = it * NTH + tid;
      int row = idx / 48, c8 = idx % 48;
      float4v v0 = *(const float4v*)(xb + row * DIM + c8 * 8);
      float4v v1 = *(const float4v*)(xb + row * DIM + c8 * 8 + 4);
      ushort8v u;
      u[0]=f2bf(v0[0]); u[1]=f2bf(v0[1]); u[2]=f2bf(v0[2]); u[3]=f2bf(v0[3]);
      u[4]=f2bf(v1[0]); u[5]=f2bf(v1[1]); u[6]=f2bf(v1[2]); u[7]=f2bf(v1[3]);
      int byte = (row * 768 + c8 * 16) ^ ((row & 7) << 4);
      *(ushort8v*)(lds + L_X + byte) = u;
    }
  }
  __syncthreads();                               // X visible; WD landed
  st_wr(lds + L_W, tid, st);                     // WD -> W
  __syncthreads();                               // WD visible
  st_load(imgc + IMG_WUP, tid, st);              // WUP; lands under G1-moe

  // ---- G1-moe: t1 = X @ WdT -> [64][32]; prob*gelu -> Hs ----
  {
    float4v hv = {};
    int raX = band * 16 + lrow, sA = (raX & 7) << 4, baX = raX * 768 + g4 * 16;
    int rbW = chh * 16 + lrow, sB = (rbW & 7) << 4, baW = rbW * 768 + g4 * 16;
    #pragma unroll
    for (int ks = 0; ks < 12; ++ks) {
      bf16x8 a = *(const bf16x8*)(lds + L_X + ((baX + ks * 64) ^ sA));
      bf16x8 b = *(const bf16x8*)(lds + L_W + ((baW + ks * 64) ^ sB));
      hv = __builtin_amdgcn_mfma_f32_16x16x32_bf16(a, b, hv, 0, 0, 0);
    }
    int colc = chh * 16 + lrow; int e = colc >> 3;
    #pragma unroll
    for (int r = 0; r < 4; ++r) {
      int row = band * 16 + g4 * 4 + r;
      int token = blockRow + row;
      float p = 0.f;
      if (e < 3) {
        int i0 = ti[token * 2], i1 = ti[token * 2 + 1];
        if (i0 == e) p += tp[token * 2];
        if (i1 == e) p += tp[token * 2 + 1];
      }
      float gv = p * gelu_f(hv[r]);
      int byte = gt_addr(row, colc >> 3) + ((colc & 7) << 1);
      *(unsigned short*)(lds + L_HS + byte) = f2bf(gv);
    }
  }
  __syncthreads();                               // (c0) Hs visible; W readers done; WUP landed
  st_wr(lds + L_W, tid, st);                     // WUP -> W
  __syncthreads();                               // (d0) WUP visible
  st_load(imgc + IMG_W1, tid, st);               // W1[0]; lands under G2-moe

  // ---- G2-moe: acc = Hs @ WupT (K=32) ----
  float4v acc[2][6] = {};
  {
    bf16x8 A[2];
    #pragma unroll
    for (int mt = 0; mt < 2; ++mt) {
      int ra = wr * 32 + mt * 16 + lrow;
      A[mt] = *(const bf16x8*)(lds + L_HS + gt_addr(ra, g4));
    }
    #pragma unroll
    for (int nt = 0; nt < 6; ++nt) {
      int rd = wc * 96 + nt * 16 + lrow;
      bf16x8 b = *(const bf16x8*)(lds + L_W + gt_addr(rd, g4));
      acc[0][nt] = __builtin_amdgcn_mfma_f32_16x16x32_bf16(A[0], b, acc[0][nt], 0, 0, 0);
      acc[1][nt] = __builtin_amdgcn_mfma_f32_16x16x32_bf16(A[1], b, acc[1][nt], 0, 0, 0);
    }
  }

  // ---- main loop: 48 chunks; every staged load hidden under a full compute phase ----
  for (int h = 0; h < NCH; ++h) {
    __syncthreads();                             // (a) W readers done; W1[h] landed
    st_wr(lds + L_W, tid, st);                   // W1[h] -> W
    __syncthreads();                             // (b) W1c visible
    st_load(imgc + IMG_W2 + h * 24576, tid, st); // W2[h]; lands under G1

    // G1: H = X @ W1c -> [64][32]
    float4v hv = {};
    {
      int raX = band * 16 + lrow, sA = (raX & 7) << 4, baX = raX * 768 + g4 * 16;
      int rbW = chh * 16 + lrow, sB = (rbW & 7) << 4, baW = rbW * 768 + g4 * 16;
      #pragma unroll
      for (int ks = 0; ks < 12; ++ks) {
        bf16x8 a = *(const bf16x8*)(lds + L_X + ((baX + ks * 64) ^ sA));
        bf16x8 b = *(const bf16x8*)(lds + L_W + ((baW + ks * 64) ^ sB));
        hv = __builtin_amdgcn_mfma_f32_16x16x32_bf16(a, b, hv, 0, 0, 0);
      }
    }
    // bias + gelu -> Hs (group-tiled)
    {
      int colc = chh * 16 + lrow;
      float bb = b1[h * CHW + colc];
      #pragma unroll
      for (int r = 0; r < 4; ++r) {
        int row = band * 16 + g4 * 4 + r;
        float gv = gelu_f(hv[r] + bb);
        int byte = gt_addr(row, colc >> 3) + ((colc & 7) << 1);
        *(unsigned short*)(lds + L_HS + byte) = f2bf(gv);
      }
    }
    __syncthreads();                             // (c) Hs visible; W readers done; W2[h] landed
    st_wr(lds + L_W, tid, st);                   // W2[h] -> W
    __syncthreads();                             // (d) W2c visible
    if (h < NCH - 1)
      st_load(imgc + IMG_W1 + (h + 1) * 24576, tid, st);  // W1[h+1]; lands under G2

    // G2: acc += Hs @ W2c (K=32)
    {
      bf16x8 A[2];
      #pragma unroll
      for (int mt = 0; mt < 2; ++mt) {
        int ra = wr * 32 + mt * 16 + lrow;
        A[mt] = *(const bf16x8*)(lds + L_HS + gt_addr(ra, g4));
      }
      #pragma unroll
      for (int nt = 0; nt < 6; ++nt) {
        int rd = wc * 96 + nt * 16 + lrow;
        bf16x8 b = *(const bf16x8*)(lds + L_W + gt_addr(rd, g4));
        acc[0][nt] = __builtin_amdgcn_mfma_f32_16x16x32_bf16(A[0], b, acc[0][nt], 0, 0, 0);
        acc[1][nt] = __builtin_amdgcn_mfma_f32_16x16x32_bf16(A[1], b, acc[1][nt], 0, 0, 0);
      }
    }
  }

  // ---- epilogue: + b2, store f32 ----
  #pragma unroll
  for (int nt = 0; nt < 6; ++nt) {
    int col = wc * 96 + nt * 16 + lrow;
    float bb = b2[col];
    #pragma unroll
    for (int mt = 0; mt < 2; ++mt) {
      #pragma unroll
      for (int r = 0; r < 4; ++r) {
        int row = wr * 32 + mt * 16 + g4 * 4 + r;
        out[(size_t)(blockRow + row) * DIM + col] = acc[mt][nt][r] + bb;
      }
    }
  }
}

extern "C" void kernel_launch(void* const* d_in, const int* in_sizes, int n_in,
                              void* d_out, int out_size, void* d_ws, size_t ws_size,
                              hipStream_t stream) {
  const float* x          = (const float*)d_in[0];
  const float* topk_probs = (const float*)d_in[2];
  const int*   topk_idx   = (const int*)  d_in[3];
  const float* w_down     = (const float*)d_in[4];
  const float* w_up       = (const float*)d_in[5];
  const float* W1         = (const float*)d_in[6];
  const float* b1         = (const float*)d_in[7];
  const float* W2         = (const float*)d_in[8];
  const float* b2         = (const float*)d_in[9];
  float* out = (float*)d_out;

  if (ws_size < WS_NEED) return;

  hipFuncSetAttribute(reinterpret_cast<const void*>(fused_k),
                      hipFuncAttributeMaxDynamicSharedMemorySize, LDSZ);

  unsigned short* img = (unsigned short*)d_ws;
  pack_k<<<(NELEMS + 255) / 256, 256, 0, stream>>>(W1, W2, w_down, w_up, img);
  fused_k<<<NBLK, NTH, LDSZ, stream>>>(x, topk_probs, topk_idx, b1, b2, img, out);
}

// Round 12
// 276.887 us; speedup vs baseline: 2.4204x; 1.0259x over previous
//
#include <hip/hip_runtime.h>
#include <hip/hip_bf16.h>

typedef __attribute__((ext_vector_type(4))) float float4v;
typedef __attribute__((ext_vector_type(8))) __bf16 bf16x8;
typedef __attribute__((ext_vector_type(8))) unsigned short ushort8v;

constexpr int NTOK = 50176;
constexpr int DIM  = 384;
constexpr int HID  = 1536;
constexpr int BM   = 64;          // tokens/block
constexpr int NTH  = 512;
constexpr int NBLK = NTOK / BM;   // 784
constexpr int CHW  = 32;          // hidden chunk width
constexpr int NCH  = HID / CHW;   // 48

// workspace (byte offsets) — bf16 images, 24KB per chunk
// W1-type [32 f][384 d]: 768B rows, pre-swizzled ^(f&7)<<4 — staged into LDS (x4 reuse)
// W2-type [384 d][32 k]: PLAIN LINEAR — read directly from global/L2 as B-frags (x2 reuse)
constexpr int IMG_WD  = 0;                      // W1-type [32][384]
constexpr int IMG_WUP = 24576;                  // linear  [384][32]
constexpr int IMG_W1  = 49152;                  // 48 x W1-type
constexpr int IMG_W2  = 49152 + 48 * 12288 * 2; // 48 x linear  (= 614400 elems *2B)
constexpr size_t WS_NEED = 2408448;
constexpr int NELEMS = 1204224;

// LDS (80 KiB/block => exactly 2 blocks/CU)
constexpr int L_X  = 0;        // 48K  X [64][384] bf16, 768B rows, swz (r&7)<<4 (persistent)
constexpr int L_W  = 49152;    // 24K  W1-chunk buffer (WD / W1c), swizzled rows
constexpr int L_HS = 73728;    // 8K   Hs double buffer: 2 x [64 tok][32 f] group-tiled
constexpr int LDSZ = 81920;

__device__ __forceinline__ unsigned short f2bf(float f) {
  __hip_bfloat16 h = __float2bfloat16(f);
  return *reinterpret_cast<unsigned short*>(&h);
}

__device__ __forceinline__ float gelu_f(float v) {
  float u = 0.7978845608f * (v + 0.044715f * v * v * v);
  float e = __expf(2.0f * u);
  float t = 1.0f - 2.0f / (e + 1.0f);
  return 0.5f * v * (1.0f + t);
}

// group-tiled byte address for [rows][32 cols] bf16: row r, 16B k-slot s
// addr = (r/8)*512 + s*128 + (r%8)*16  -> uniform 8 lanes/slot reads: free 2-way
__device__ __forceinline__ int gt_addr(int r, int s) {
  return ((r >> 3) << 9) + (s << 7) + ((r & 7) << 4);
}

// ---- T14 staging (W1 only now): load after barrier A, write after barrier B ----
__device__ __forceinline__ void st_load(const char* src, int tid, ushort8v st[3]) {
  #pragma unroll
  for (int j = 0; j < 3; ++j)
    st[j] = *(const ushort8v*)(src + tid * 16 + j * 8192);
}
__device__ __forceinline__ void st_wr(char* dst, int tid, const ushort8v st[3]) {
  #pragma unroll
  for (int j = 0; j < 3; ++j)
    *(ushort8v*)(dst + tid * 16 + j * 8192) = st[j];
}

// ---------------- pack kernel ----------------
__global__ __launch_bounds__(256) void pack_k(
    const float* __restrict__ W1, const float* __restrict__ W2,
    const float* __restrict__ wd, const float* __restrict__ wu,
    unsigned short* __restrict__ img)
{
  int i = blockIdx.x * 256 + threadIdx.x;
  if (i >= NELEMS) return;
  if (i < 12288) {                               // WD (W1-type): [32 f][384 d] swz
    int f = i / 384; int inb = (i % 384) * 2;
    int d = (inb ^ ((f & 7) << 4)) >> 1;
    float v = (f < 24) ? wd[(f >> 3) * (DIM * 8) + d * 8 + (f & 7)] : 0.f;
    img[i] = f2bf(v);
  } else if (i < 24576) {                        // WUP linear [384 d][32 c]
    int j = i - 12288;
    int d = j / 32, c = j % 32;
    float v = (c < 24) ? wu[c * DIM + d] : 0.f;
    img[i] = f2bf(v);
  } else if (i < 24576 + 48 * 12288) {           // W1 chunks (W1-type swz)
    int j = i - 24576; int h = j / 12288; int jc = j % 12288;
    int f = jc / 384; int inb = (jc % 384) * 2;
    int d = (inb ^ ((f & 7) << 4)) >> 1;
    img[i] = f2bf(W1[d * HID + h * CHW + f]);
  } else {                                       // W2 chunks linear [384 d][32 k]
    int j = i - 24576 - 48 * 12288; int h = j / 12288; int jc = j % 12288;
    int d = jc / 32, k = jc % 32;
    img[i] = f2bf(W2[(h * CHW + k) * DIM + d]);
  }
}

// ---------------- fused MLP + MoE-LoRA ----------------
__global__ __launch_bounds__(NTH, 4) void fused_k(
    const float* __restrict__ x,
    const float* __restrict__ tp,
    const int*   __restrict__ ti,
    const float* __restrict__ b1,
    const float* __restrict__ b2,
    const unsigned short* __restrict__ img,
    float* __restrict__ out)
{
  extern __shared__ char lds[];
  const int tid = threadIdx.x, wid = tid >> 6, lane = tid & 63;
  const int lrow = lane & 15, g4 = lane >> 4;
  const int blockRow = blockIdx.x * BM;
  const char* imgc = (const char*)img;

  const int band = wid >> 1, chh = wid & 1;      // G1 grid: 4 bands x 2 col-halves
  const int wr = wid >> 2, wc = wid & 3;         // G2 grid: 2M x 4N

  ushort8v st[3];                                // 12 regs; W1 pipeline only

  // ---- prologue: issue WD; X f32->bf16 -> L_X (disjoint from L_W: write WD early) ----
  st_load(imgc + IMG_WD, tid, st);
  {
    const float* xb = x + (size_t)blockRow * DIM;
    #pragma unroll
    for (int it = 0; it < 6; ++it) {
      int idx = it * NTH + tid;
      int row = idx / 48, c8 = idx % 48;
      float4v v0 = *(const float4v*)(xb + row * DIM + c8 * 8);
      float4v v1 = *(const float4v*)(xb + row * DIM + c8 * 8 + 4);
      ushort8v u;
      u[0]=f2bf(v0[0]); u[1]=f2bf(v0[1]); u[2]=f2bf(v0[2]); u[3]=f2bf(v0[3]);
      u[4]=f2bf(v1[0]); u[5]=f2bf(v1[1]); u[6]=f2bf(v1[2]); u[7]=f2bf(v1[3]);
      int byte = (row * 768 + c8 * 16) ^ ((row & 7) << 4);
      *(ushort8v*)(lds + L_X + byte) = u;
    }
  }
  st_wr(lds + L_W, tid, st);                     // WD -> L_W (reg-dep waits; hidden by X stage)
  st_load(imgc + IMG_W1, tid, st);               // W1[0]; lands under G1-moe
  __syncthreads();                               // X + WD visible

  // ---- G1-moe: t1 = X @ WdT -> [64][32]; prob*gelu -> Hs[0] ----
  {
    float4v hv = {};
    int raX = band * 16 + lrow, sA = (raX & 7) << 4, baX = raX * 768 + g4 * 16;
    int rbW = chh * 16 + lrow, sB = (rbW & 7) << 4, baW = rbW * 768 + g4 * 16;
    #pragma unroll
    for (int ks = 0; ks < 12; ++ks) {
      bf16x8 a = *(const bf16x8*)(lds + L_X + ((baX + ks * 64) ^ sA));
      bf16x8 b = *(const bf16x8*)(lds + L_W + ((baW + ks * 64) ^ sB));
      hv = __builtin_amdgcn_mfma_f32_16x16x32_bf16(a, b, hv, 0, 0, 0);
    }
    int colc = chh * 16 + lrow; int e = colc >> 3;
    #pragma unroll
    for (int r = 0; r < 4; ++r) {
      int row = band * 16 + g4 * 4 + r;
      int token = blockRow + row;
      float p = 0.f;
      if (e < 3) {
        int i0 = ti[token * 2], i1 = ti[token * 2 + 1];
        if (i0 == e) p += tp[token * 2];
        if (i1 == e) p += tp[token * 2 + 1];
      }
      float gv = p * gelu_f(hv[r]);
      int byte = gt_addr(row, colc >> 3) + ((colc & 7) << 1);
      *(unsigned short*)(lds + L_HS + byte) = f2bf(gv);
    }
  }
  __syncthreads();                               // bB-moe: Hs[0] visible; WD readers done
  st_wr(lds + L_W, tid, st);                     // W1[0] -> L_W

  // ---- G2-moe: acc = Hs[0] @ WupT (K=32); B DIRECT from global WUP ----
  float4v acc[2][6] = {};
  {
    bf16x8 bfr[6];
    #pragma unroll
    for (int nt = 0; nt < 6; ++nt) {
      int rd = wc * 96 + nt * 16 + lrow;
      bfr[nt] = *(const bf16x8*)(imgc + IMG_WUP + rd * 64 + g4 * 16);
    }
    bf16x8 A[2];
    #pragma unroll
    for (int mt = 0; mt < 2; ++mt) {
      int ra = wr * 32 + mt * 16 + lrow;
      A[mt] = *(const bf16x8*)(lds + L_HS + gt_addr(ra, g4));
    }
    #pragma unroll
    for (int nt = 0; nt < 6; ++nt) {
      acc[0][nt] = __builtin_amdgcn_mfma_f32_16x16x32_bf16(A[0], bfr[nt], acc[0][nt], 0, 0, 0);
      acc[1][nt] = __builtin_amdgcn_mfma_f32_16x16x32_bf16(A[1], bfr[nt], acc[1][nt], 0, 0, 0);
    }
  }

  // ---- main loop: 48 chunks, 2 barriers/chunk; W1 LDS-staged, W2 direct-global ----
  for (int h = 0; h < NCH; ++h) {
    const int hb = 4096 - ((h & 1) << 12);       // G1[h] writes Hs[1-(h&1)] (moe used Hs[0])
    __syncthreads();                             // bA: W1[h] visible; Hs[target] readers done
    if (h < NCH - 1)
      st_load(imgc + IMG_W1 + (h + 1) * 24576, tid, st);  // W1[h+1]; lands under G1

    // G1: H = X @ W1c -> [64][32]
    float4v hv = {};
    {
      int raX = band * 16 + lrow, sA = (raX & 7) << 4, baX = raX * 768 + g4 * 16;
      int rbW = chh * 16 + lrow, sB = (rbW & 7) << 4, baW = rbW * 768 + g4 * 16;
      #pragma unroll
      for (int ks = 0; ks < 12; ++ks) {
        bf16x8 a = *(const bf16x8*)(lds + L_X + ((baX + ks * 64) ^ sA));
        bf16x8 b = *(const bf16x8*)(lds + L_W + ((baW + ks * 64) ^ sB));
        hv = __builtin_amdgcn_mfma_f32_16x16x32_bf16(a, b, hv, 0, 0, 0);
      }
    }
    // bias + gelu -> Hs[target] (group-tiled)
    {
      int colc = chh * 16 + lrow;
      float bb = b1[h * CHW + colc];
      #pragma unroll
      for (int r = 0; r < 4; ++r) {
        int row = band * 16 + g4 * 4 + r;
        float gv = gelu_f(hv[r] + bb);
        int byte = gt_addr(row, colc >> 3) + ((colc & 7) << 1);
        *(unsigned short*)(lds + L_HS + hb + byte) = f2bf(gv);
      }
    }
    __syncthreads();                             // bB: Hs[target] visible; G1 done with L_W
    if (h < NCH - 1)
      st_wr(lds + L_W, tid, st);                 // W1[h+1] -> L_W

    // G2: acc += Hs @ W2c (K=32); B direct from global (L2-hot, batched loads)
    {
      const char* w2b = imgc + IMG_W2 + h * 24576;
      bf16x8 bfr[6];
      #pragma unroll
      for (int nt = 0; nt < 6; ++nt) {
        int rd = wc * 96 + nt * 16 + lrow;
        bfr[nt] = *(const bf16x8*)(w2b + rd * 64 + g4 * 16);
      }
      bf16x8 A[2];
      #pragma unroll
      for (int mt = 0; mt < 2; ++mt) {
        int ra = wr * 32 + mt * 16 + lrow;
        A[mt] = *(const bf16x8*)(lds + L_HS + hb + gt_addr(ra, g4));
      }
      #pragma unroll
      for (int nt = 0; nt < 6; ++nt) {
        acc[0][nt] = __builtin_amdgcn_mfma_f32_16x16x32_bf16(A[0], bfr[nt], acc[0][nt], 0, 0, 0);
        acc[1][nt] = __builtin_amdgcn_mfma_f32_16x16x32_bf16(A[1], bfr[nt], acc[1][nt], 0, 0, 0);
      }
    }
  }

  // ---- epilogue: + b2, store f32 ----
  #pragma unroll
  for (int nt = 0; nt < 6; ++nt) {
    int col = wc * 96 + nt * 16 + lrow;
    float bb = b2[col];
    #pragma unroll
    for (int mt = 0; mt < 2; ++mt) {
      #pragma unroll
      for (int r = 0; r < 4; ++r) {
        int row = wr * 32 + mt * 16 + g4 * 4 + r;
        out[(size_t)(blockRow + row) * DIM + col] = acc[mt][nt][r] + bb;
      }
    }
  }
}

extern "C" void kernel_launch(void* const* d_in, const int* in_sizes, int n_in,
                              void* d_out, int out_size, void* d_ws, size_t ws_size,
                              hipStream_t stream) {
  const float* x          = (const float*)d_in[0];
  const float* topk_probs = (const float*)d_in[2];
  const int*   topk_idx   = (const int*)  d_in[3];
  const float* w_down     = (const float*)d_in[4];
  const float* w_up       = (const float*)d_in[5];
  const float* W1         = (const float*)d_in[6];
  const float* b1         = (const float*)d_in[7];
  const float* W2         = (const float*)d_in[8];
  const float* b2         = (const float*)d_in[9];
  float* out = (float*)d_out;

  if (ws_size < WS_NEED) return;

  hipFuncSetAttribute(reinterpret_cast<const void*>(fused_k),
                      hipFuncAttributeMaxDynamicSharedMemorySize, LDSZ);

  unsigned short* img = (unsigned short*)d_ws;
  pack_k<<<(NELEMS + 255) / 256, 256, 0, stream>>>(W1, W2, w_down, w_up, img);
  fused_k<<<NBLK, NTH, LDSZ, stream>>>(x, topk_probs, topk_idx, b1, b2, img, out);
}